// Round 7
// baseline (102.851 us; speedup 1.0000x reference)
//
#include <hip/hip_runtime.h>
#include <stdint.h>

#define N_ATOMS 2048
#define KNN     12
#define CAP     128
#define QCAP    4736     // LDS record queue (expected ~3600, worst-mean+20sd)
#define CPB     4        // centers per block
#define NBLK    (N_ATOMS / CPB)          // 512 blocks
#define NEDGE   (N_ATOMS * KNN)
#define OFF_EDGE 0
#define OFF_DIST (3 * NEDGE)
#define OFF_SRC  (OFF_DIST + NEDGE)
#define OFF_DST  (OFF_SRC + NEDGE)
#define OFF_NUM  (OFF_DST + NEDGE)
#define DELTA   5e-4f    // cheap-vs-exact frac guard band (validated R3/R6)

// One kernel, one node. 512 blocks x 256 threads, 4 centers per block.
// Phase 1 (per block, once): classify all 2048 atoms (8/thread, float4-packed
//   loads), build LDS queue of valid replica records (px,py,pz,meta):
//   j=13 at deterministic slots 0..2047, extras appended via wave-ballot
//   prefix compaction (ONE LDS atomic per wave).
// Phase 2 (x4 centers): threshold-scan queue via ds_read_b128, exact top-12
//   via 64-lane shfl-min on (d2_bits<<32 | j*2048+i) keys == lax.top_k.
__global__ __launch_bounds__(256) void knn_fused(
    const float* __restrict__ pos, const float* __restrict__ cell,
    const int* __restrict__ numbers, float* __restrict__ out)
{
    __shared__ float4 sh_rec[QCAP];
    __shared__ float sh_shift[27][3];
    __shared__ unsigned long long sh_keys[CAP];
    __shared__ int sh_qn, sh_cnt;

    const int tid = threadIdx.x;
    const int lane = tid & 63;

    float c[9];
#pragma unroll
    for (int q = 0; q < 9; ++q) c[q] = cell[q];

    // inverse via double adjugate, rounded to f32 (identical to passing rounds)
    double a00 = c[0], a01 = c[1], a02 = c[2];
    double a10 = c[3], a11 = c[4], a12 = c[5];
    double a20 = c[6], a21 = c[7], a22 = c[8];
    double det = a00 * (a11 * a22 - a12 * a21)
               - a01 * (a10 * a22 - a12 * a20)
               + a02 * (a10 * a21 - a11 * a20);
    double id = 1.0 / det;
    float M[9];  // frac_d = fma(pz,M[6+d], fma(py,M[3+d], px*M[d]))
    M[0] = (float)(( a11 * a22 - a12 * a21) * id);
    M[1] = (float)((-(a01 * a22 - a02 * a21)) * id);
    M[2] = (float)(( a01 * a12 - a02 * a11) * id);
    M[3] = (float)((-(a10 * a22 - a12 * a20)) * id);
    M[4] = (float)(( a00 * a22 - a02 * a20) * id);
    M[5] = (float)((-(a00 * a12 - a02 * a10)) * id);
    M[6] = (float)(( a10 * a21 - a11 * a20) * id);
    M[7] = (float)((-(a00 * a21 - a01 * a20)) * id);
    M[8] = (float)(( a00 * a11 - a01 * a10) * id);

    float rn0 = sqrtf(c[0]*c[0] + c[1]*c[1] + c[2]*c[2]);
    float rn1 = sqrtf(c[3]*c[3] + c[4]*c[4] + c[5]*c[5]);
    float rn2 = sqrtf(c[6]*c[6] + c[7]*c[7] + c[8]*c[8]);
    float dxm = 0.1f * fminf(rn0, fminf(rn1, rn2));
    const float e0 = dxm / rn0, e1 = dxm / rn1, e2 = dxm / rn2;

    float vol = (float)fabs(det);
    const float T0 = powf(3.0f * 48.0f * vol / (4.0f * 3.14159265f * (float)N_ATOMS), 2.0f / 3.0f);

    if (tid < 27) {
        int j = tid;
        float o0 = (float)(j / 9 - 1);
        float o1 = (float)((j / 3) % 3 - 1);
        float o2 = (float)(j % 3 - 1);
        sh_shift[j][0] = __fadd_rn(__fadd_rn(__fmul_rn(o0, c[0]), __fmul_rn(o1, c[3])), __fmul_rn(o2, c[6]));
        sh_shift[j][1] = __fadd_rn(__fadd_rn(__fmul_rn(o0, c[1]), __fmul_rn(o1, c[4])), __fmul_rn(o2, c[7]));
        sh_shift[j][2] = __fadd_rn(__fadd_rn(__fmul_rn(o0, c[2]), __fmul_rn(o1, c[5])), __fmul_rn(o2, c[8]));
    }
    if (tid == 0) sh_qn = N_ATOMS;   // slots 0..2047 reserved for j=13
    if (blockIdx.x < N_ATOMS / 256) {
        int mm = blockIdx.x * 256 + tid;
        out[OFF_NUM + mm] = (float)numbers[mm];
    }
    __syncthreads();

    // ---------------- Phase 1: classify 8 atoms/thread, build queue ---------
    {
        const float4* pv = reinterpret_cast<const float4*>(pos + tid * 24);
        float4 w0 = pv[0], w1 = pv[1], w2 = pv[2], w3 = pv[3], w4 = pv[4], w5 = pv[5];
        float ax[8] = {w0.x, w0.w, w1.z, w2.y, w3.x, w3.w, w4.z, w5.y};
        float ay[8] = {w0.y, w1.x, w1.w, w2.z, w3.y, w4.x, w4.w, w5.z};
        float az[8] = {w0.z, w1.y, w2.x, w2.w, w3.z, w4.y, w5.x, w5.w};
        const unsigned long long lmask_lt = (1ull << lane) - 1ull;

#pragma unroll
        for (int q = 0; q < 8; ++q) {
            const int i = tid * 8 + q;
            const float pxi = ax[q], pyi = ay[q], pzi = az[q];
            float fr0 = __fmaf_rn(pzi, M[6], __fmaf_rn(pyi, M[3], __fmul_rn(pxi, M[0])));
            float fr1 = __fmaf_rn(pzi, M[7], __fmaf_rn(pyi, M[4], __fmul_rn(pxi, M[1])));
            float fr2 = __fmaf_rn(pzi, M[8], __fmaf_rn(pyi, M[5], __fmul_rn(pxi, M[2])));
            int alt0 = 1, has0 = 0, unc0 = 0;
            if (fr0 <= e0 + DELTA)              { alt0 = 2; has0 = 1; unc0 = (fr0 > e0 - DELTA); }
            else if (fr0 >= 1.0f - e0 - DELTA)  { alt0 = 0; has0 = 1; unc0 = (fr0 < 1.0f - e0 + DELTA); }
            int alt1 = 1, has1 = 0, unc1 = 0;
            if (fr1 <= e1 + DELTA)              { alt1 = 2; has1 = 1; unc1 = (fr1 > e1 - DELTA); }
            else if (fr1 >= 1.0f - e1 - DELTA)  { alt1 = 0; has1 = 1; unc1 = (fr1 < 1.0f - e1 + DELTA); }
            int alt2 = 1, has2 = 0, unc2 = 0;
            if (fr2 <= e2 + DELTA)              { alt2 = 2; has2 = 1; unc2 = (fr2 > e2 - DELTA); }
            else if (fr2 >= 1.0f - e2 - DELTA)  { alt2 = 0; has2 = 1; unc2 = (fr2 < 1.0f - e2 + DELTA); }

            // j = 13 home replica: always valid, deterministic slot i
            {
                float px = __fadd_rn(pxi, sh_shift[13][0]);
                float py = __fadd_rn(pyi, sh_shift[13][1]);
                float pz = __fadd_rn(pzi, sh_shift[13][2]);
                sh_rec[i] = make_float4(px, py, pz,
                    __uint_as_float((unsigned)(i | (13 << 11))));
            }

            // extras: combo bitmask s=1..7 (bit s set iff combo exists)
            unsigned en = 0;
#pragma unroll
            for (int s = 1; s < 8; ++s) {
                bool ok = ((s & 1) ? has0 : 1) && ((s & 2) ? has1 : 1) && ((s & 4) ? has2 : 1);
                en |= ok ? (1u << s) : 0u;
            }
            unsigned long long B[8];
            int pc[8];
            int tot = 0;
#pragma unroll
            for (int s = 1; s < 8; ++s) {
                B[s] = __ballot((en >> s) & 1u);
                pc[s] = __popcll(B[s]);
                tot += pc[s];
            }
            int base = 0;
            if (lane == 0 && tot) base = atomicAdd(&sh_qn, tot);
            base = __shfl(base, 0, 64);
            int run = base;
#pragma unroll
            for (int s = 1; s < 8; ++s) {
                if ((en >> s) & 1u) {
                    int slot = run + __popcll(B[s] & lmask_lt);
                    if (slot < QCAP) {
                        int k0 = (s & 1) ? alt0 : 1;
                        int k1 = (s & 2) ? alt1 : 1;
                        int k2 = (s & 4) ? alt2 : 1;
                        int j = k0 * 9 + k1 * 3 + k2;
                        int u = ((s & 1) & unc0) | (((s >> 1) & 1) & unc1) | (((s >> 2) & 1) & unc2);
                        float px = __fadd_rn(pxi, sh_shift[j][0]);
                        float py = __fadd_rn(pyi, sh_shift[j][1]);
                        float pz = __fadd_rn(pzi, sh_shift[j][2]);
                        sh_rec[slot] = make_float4(px, py, pz,
                            __uint_as_float((unsigned)(i | (j << 11) | (u << 16))));
                    }
                }
                run += pc[s];
            }
        }
    }
    __syncthreads();
    const int qn = min(sh_qn, QCAP);

    // ---------------- Phase 2: 4 centers, scan + exact top-12 ---------------
    for (int ci = 0; ci < CPB; ++ci) {
        const int a = blockIdx.x * CPB + ci;
        const float cx = pos[a * 3 + 0];
        const float cy = pos[a * 3 + 1];
        const float cz = pos[a * 3 + 2];
        const float ccv = __fadd_rn(__fadd_rn(__fmul_rn(cx, cx), __fmul_rn(cy, cy)), __fmul_rn(cz, cz));
        float T = T0;
        int cnt = 0;

        for (int att = 0; att < 16; ++att) {
            if (tid == 0) sh_cnt = 0;
            __syncthreads();
            for (int it = tid; it < qn; it += 256) {
                float4 rec = sh_rec[it];
                float pp  = __fadd_rn(__fadd_rn(__fmul_rn(rec.x, rec.x), __fmul_rn(rec.y, rec.y)), __fmul_rn(rec.z, rec.z));
                float dot = __fmaf_rn(cz, rec.z, __fmaf_rn(cy, rec.y, __fmul_rn(cx, rec.x)));
                float d2  = __fsub_rn(__fadd_rn(ccv, pp), __fmul_rn(2.0f, dot));
                if (d2 < T) {
                    unsigned meta = __float_as_uint(rec.w);
                    int i = (int)(meta & 2047u);
                    int j = (int)((meta >> 11) & 31u);
                    if (i == a && j == 13) continue;          // self
                    if (meta >> 16) {                          // boundary band: exact check
                        float f0 = __fmaf_rn(rec.z, M[6], __fmaf_rn(rec.y, M[3], __fmul_rn(rec.x, M[0])));
                        float f1 = __fmaf_rn(rec.z, M[7], __fmaf_rn(rec.y, M[4], __fmul_rn(rec.x, M[1])));
                        float f2 = __fmaf_rn(rec.z, M[8], __fmaf_rn(rec.y, M[5], __fmul_rn(rec.x, M[2])));
                        bool v = (f0 >= -e0) && (f0 <= 1.0f + e0)
                              && (f1 >= -e1) && (f1 <= 1.0f + e1)
                              && (f2 >= -e2) && (f2 <= 1.0f + e2);
                        if (!v) continue;
                    }
                    int slot = atomicAdd(&sh_cnt, 1);
                    if (slot < CAP)
                        sh_keys[slot] = ((unsigned long long)__float_as_uint(d2) << 32)
                                      | (unsigned)(j * N_ATOMS + i);
                }
            }
            __syncthreads();
            cnt = sh_cnt;
            __syncthreads();   // protect sh_cnt vs next-iter reset
            if (cnt >= KNN && cnt <= CAP) break;
            T = (cnt < KNN) ? T * 2.0f : T * 0.5f;
        }
        if (cnt > CAP) cnt = CAP;

        if (tid < 64) {
            const unsigned long long MAXK = ~0ull;
            unsigned long long k0 = (tid < cnt) ? sh_keys[tid] : MAXK;
            unsigned long long k1 = (tid + 64 < cnt) ? sh_keys[tid + 64] : MAXK;
            unsigned long long lo = (k0 < k1) ? k0 : k1;
            unsigned long long hi = (k0 < k1) ? k1 : k0;
#pragma unroll
            for (int r = 0; r < KNN; ++r) {
                unsigned long long mn = lo;
#pragma unroll
                for (int off = 32; off; off >>= 1) {
                    unsigned long long o = __shfl_xor(mn, off, 64);
                    mn = (o < mn) ? o : mn;
                }
                if (lo == mn) { lo = hi; hi = MAXK; }  // consume winner
                if (tid == r) {
                    unsigned mval = (unsigned)(mn & 0xffffffffu);
                    float d2 = __uint_as_float((unsigned)(mn >> 32));
                    int ii = (int)(mval & (N_ATOMS - 1));
                    int jj = (int)(mval >> 11);
                    float px = __fadd_rn(pos[ii * 3 + 0], sh_shift[jj][0]);
                    float py = __fadd_rn(pos[ii * 3 + 1], sh_shift[jj][1]);
                    float pz = __fadd_rn(pos[ii * 3 + 2], sh_shift[jj][2]);
                    int eo = a * KNN + r;
                    out[OFF_EDGE + 3 * eo + 0] = __fsub_rn(px, cx);
                    out[OFF_EDGE + 3 * eo + 1] = __fsub_rn(py, cy);
                    out[OFF_EDGE + 3 * eo + 2] = __fsub_rn(pz, cz);
                    out[OFF_DIST + eo] = sqrtf(fmaxf(d2, 0.0f));
                    out[OFF_SRC + eo]  = (float)ii;
                    out[OFF_DST + eo]  = (float)a;
                }
            }
        }
        __syncthreads();   // protect sh_keys/sh_cnt before next center
    }
}

extern "C" void kernel_launch(void* const* d_in, const int* in_sizes, int n_in,
                              void* d_out, int out_size, void* d_ws, size_t ws_size,
                              hipStream_t stream) {
    const float* pos     = (const float*)d_in[0];
    const float* cell    = (const float*)d_in[1];
    const int*   numbers = (const int*)d_in[2];
    float*       out     = (float*)d_out;
    (void)d_ws; (void)ws_size;

    hipLaunchKernelGGL(knn_fused, dim3(NBLK), dim3(256), 0, stream,
                       pos, cell, numbers, out);
}